// Round 3
// baseline (198.223 us; speedup 1.0000x reference)
//
#include <hip/hip_runtime.h>
#include <stdint.h>

// proj = einsum('bit,ih->tbh', x, W); scan: h=relu(p+0.8h(1-y)); y=thr(h+b,1).
// B=64, K=512, T=512, H=1024 fp32. Output: final y (64x1024).
//
// R8: 2 blocks/CU. R7 post-mortem: dbuf+single-drain got only 95us/46%
// MfmaUtil — with 1 block/CU all 8 waves are barrier-locked through the
// same ds_read phase (~1536 cyc/CU/iter) and MFMA phase (~3725), so phase
// bubbles can't be filled. Fix: HB 256->128, grid 64x8=512 = 2 blocks/CU;
// LDS 48KB/block (single-buffer staging; epilogue P[64][128] fp32 ALIASED
// onto the staging buffer); __launch_bounds__(512,4) caps VGPR at 128
// (acc halves to 4x4 f4 = 64 regs). Per-block k-loop reverts to the
// proven serial shape (stage -> drain+barrier -> frags+MFMA -> barrier);
// the co-resident block's MFMA covers this block's stage/epilogue stalls
// (m114: cross-block overlap is what source pipelining couldn't buy).
// Grid (64,8): all 8 h-blocks of batch b land on XCD b%8 -> x re-reads
// are L2/L3-local. P swizzle col^=((row>>2)&3)<<4: writer spreads 4
// lq-rows over 4 16-col blocks (conflict-free), reader stays row-
// contiguous (2-way, free). Accumulation order per output element is
// bit-identical to R5-R7; absmax must hold at 0.03125.

#define NB 64
#define NK 512
#define NT 512
#define NH 1024

#define TB 256     // t per block tile
#define HB 128     // h per block tile
#define KK 32      // k per step

typedef _Float16 h8_t __attribute__((ext_vector_type(8)));
typedef float    f4_t __attribute__((ext_vector_type(4)));

#define AS1 __attribute__((address_space(1)))
#define AS3 __attribute__((address_space(3)))

__device__ __forceinline__ void async_copy16(const _Float16* g, _Float16* l) {
    __builtin_amdgcn_global_load_lds((const AS1 uint32_t*)g, (AS3 uint32_t*)l, 16, 0, 0);
}

// full drain + barrier after stage: staged tile visible to all waves
__device__ __forceinline__ void wait_all_barrier() {
    __builtin_amdgcn_s_waitcnt(0);   // vmcnt(0) expcnt(0) lgkmcnt(0)
    __syncthreads();
}

// ---- pre-pass (unchanged from R6): fp32 [rows][C] -> fp16 hi/lo in
// fragment order, coalesced float4 reads, dense h8 stores.
__global__ __launch_bounds__(256) void split_tc(
    const float* __restrict__ X, const float* __restrict__ Wm,
    _Float16* __restrict__ xhi, _Float16* __restrict__ xlo,
    _Float16* __restrict__ whi, _Float16* __restrict__ wlo)
{
    const int tid = threadIdx.x;
    const int cq  = tid & 15;     // col quad 0..15
    const int u   = tid >> 4;     // row octet 0..15

    const float* src;
    _Float16 *dhi, *dlo;
    int C, col0, row0, ktbase;

    if (blockIdx.z < 32) {
        const int idx = blockIdx.y * 16 + blockIdx.x;   // 0..63
        const int b   = blockIdx.z * 2 + (idx >> 5);    // 0..63
        const int i5  = idx & 31;
        const int bx  = i5 & 7;                          // col tile 0..7
        const int by  = i5 >> 3;                         // row tile 0..3
        C      = NT;                                     // 512
        src    = X + (size_t)b * NK * NT;
        dhi    = xhi;  dlo = xlo;
        col0   = bx * 64;
        row0   = by * 128;
        ktbase = b * 16 + by * 4;
    } else {
        const int bx = blockIdx.x;                       // 0..15
        const int by = blockIdx.y;                       // 0..3
        C      = NH;                                     // 1024
        src    = Wm;
        dhi    = whi;  dlo = wlo;
        col0   = bx * 64;
        row0   = by * 128;
        ktbase = by * 4;
    }

    const float* s = src + (size_t)(row0 + u * 8) * C + col0 + cq * 4;

    f4_t v[8];
    #pragma unroll
    for (int j = 0; j < 8; ++j)
        v[j] = *(const f4_t*)(s + (size_t)j * C);

    const int kt = ktbase + (u >> 2);
    const int ck = u & 3;

    #pragma unroll
    for (int i = 0; i < 4; ++i) {
        h8_t hi, lo;
        #pragma unroll
        for (int j = 0; j < 8; ++j) {
            float f = v[j][i] * 64.0f;       // 2^6 pre-scale
            _Float16 hh = (_Float16)f;
            hi[j] = hh;
            lo[j] = (_Float16)(f - (float)hh);
        }
        const int col = col0 + cq * 4 + i;
        const int ckp = ck ^ ((col >> 1) & 3);
        const size_t off = ((size_t)kt * C + col) * 32 + (size_t)ckp * 8;
        *(h8_t*)(dhi + off) = hi;
        *(h8_t*)(dlo + off) = lo;
    }
}

// ---------------- main fused kernel (R8: 2 blocks/CU) ----------------
__global__ __launch_bounds__(512, 4) void fused_main(
    const _Float16* __restrict__ xhi, const _Float16* __restrict__ xlo,
    const _Float16* __restrict__ whi, const _Float16* __restrict__ wlo,
    const float* __restrict__ bias, float* __restrict__ out)
{
    // staging: A hi/lo 2x16KB + B hi/lo 2x8KB = 48 KB total
    __shared__ __align__(16) _Float16 SA[2][TB * KK];   // [0]=hi [1]=lo
    __shared__ __align__(16) _Float16 SB[2][HB * KK];
    // Epilogue P[64][128] fp32 (32 KB) aliases SA (free after last k-iter)
    float* Pf = (float*)&SA[0][0];

    const int tid  = threadIdx.x;
    const int lane = tid & 63;
    const int wid  = tid >> 6;     // 0..7
    const int l15  = lane & 15;
    const int lq   = lane >> 4;    // 0..3
    const int wm   = wid >> 1;     // t quarter 0..3 (64 rows each)
    const int wn   = wid & 1;      // h half 0..1 (64 cols each)

    const int b  = blockIdx.x;
    const int h0 = blockIdx.y * HB;

    // fragment LDS offsets (halfs); chunk swizzle matches pre-pass
    // (global col bits 1-2 == local l15 bits 1-2 since h0/t-offsets are x16)
    const int sw   = (l15 >> 1) & 3;
    const int aoff = ((wm * 64 + l15) * 4 + (lq ^ sw)) * 8;   // + mi*512
    const int boff = ((wn * 64 + l15) * 4 + (lq ^ sw)) * 8;   // + ni*512

    float hs = 0.0f, ys = 0.0f, bv = 0.0f;
    if (tid < HB) bv = bias[h0 + tid];

    const float INV_SCALE = 1.0f / 4096.0f;   // undo 2^6 x 2^6 operand scales

    // stage tile (tt, kt): A = 2x1024 chunks, B = 2x512 chunks; 6 copies/thread.
    auto stage = [&](int tt, int kt) {
        const _Float16* ga_hi = xhi + ((size_t)(b * 16 + kt) * NT + tt) * KK;
        const _Float16* ga_lo = xlo + ((size_t)(b * 16 + kt) * NT + tt) * KK;
        const _Float16* gb_hi = whi + ((size_t)kt * NH + h0) * KK;
        const _Float16* gb_lo = wlo + ((size_t)kt * NH + h0) * KK;
        #pragma unroll
        for (int c = 0; c < 2; ++c) {
            const int ch = tid + c * 512;
            async_copy16(ga_hi + ch * 8, &SA[0][ch * 8]);
            async_copy16(ga_lo + ch * 8, &SA[1][ch * 8]);
        }
        async_copy16(gb_hi + tid * 8, &SB[0][tid * 8]);
        async_copy16(gb_lo + tid * 8, &SB[1][tid * 8]);
    };

    f4_t acc[4][4];

    for (int tt0 = 0; tt0 < NT; tt0 += TB) {
        #pragma unroll
        for (int mi = 0; mi < 4; ++mi)
            #pragma unroll
            for (int ni = 0; ni < 4; ++ni) {
                f4_t z = {0.f, 0.f, 0.f, 0.f};
                acc[mi][ni] = z;
            }

        for (int kt = 0; kt < NK / KK; ++kt) {
            stage(tt0, kt);
            wait_all_barrier();   // staged tile landed, visible to all

            h8_t bh[4], bl[4];
            #pragma unroll
            for (int ni = 0; ni < 4; ++ni) {
                bh[ni] = *(const h8_t*)(&SB[0][boff + ni * 512]);
                bl[ni] = *(const h8_t*)(&SB[1][boff + ni * 512]);
            }
            __builtin_amdgcn_s_setprio(1);
            #pragma unroll
            for (int mi = 0; mi < 4; ++mi) {
                h8_t ah = *(const h8_t*)(&SA[0][aoff + mi * 512]);
                h8_t al = *(const h8_t*)(&SA[1][aoff + mi * 512]);
                #pragma unroll
                for (int ni = 0; ni < 4; ++ni) {
                    acc[mi][ni] = __builtin_amdgcn_mfma_f32_16x16x32_f16(ah, bh[ni], acc[mi][ni], 0, 0, 0);
                    acc[mi][ni] = __builtin_amdgcn_mfma_f32_16x16x32_f16(ah, bl[ni], acc[mi][ni], 0, 0, 0);
                    acc[mi][ni] = __builtin_amdgcn_mfma_f32_16x16x32_f16(al, bh[ni], acc[mi][ni], 0, 0, 0);
                }
            }
            __builtin_amdgcn_s_setprio(0);

            __syncthreads();   // all frag reads retired before next stage
        }

        // epilogue: 4 t-subtiles x 64 rows; P[64][128] aliased on SA.
        // Swizzle col' = col ^ (((row>>2)&3)<<4); (row>>2)&3 == lq on write.
        #pragma unroll 1
        for (int sub = 0; sub < 4; ++sub) {
            if (wm == sub) {
                #pragma unroll
                for (int mi = 0; mi < 4; ++mi)
                    #pragma unroll
                    for (int ni = 0; ni < 4; ++ni)
                        #pragma unroll
                        for (int r = 0; r < 4; ++r) {
                            const int row = mi * 16 + lq * 4 + r;
                            const int col = (wn * 64 + ni * 16 + l15) ^ (lq << 4);
                            Pf[row * 128 + col] = acc[mi][ni][r] * INV_SCALE;
                        }
            }
            __syncthreads();
            if (tid < HB) {
                const int cc = tid;   // h within block tile, 0..127
                #pragma unroll 8
                for (int m = 0; m < 64; ++m) {
                    float p = Pf[m * 128 + (cc ^ (((m >> 2) & 3) << 4))];
                    float pre = p + 0.8f * hs * (1.0f - ys);
                    hs = pre > 0.0f ? pre : 0.0f;
                    float z = hs + bv;
                    ys = (z > 1.0f) ? z : 0.0f;
                }
            }
            __syncthreads();   // scan done before next sub / next stage
        }
    }

    if (tid < HB)
        out[(size_t)b * NH + h0 + tid] = ys;
}

extern "C" void kernel_launch(void* const* d_in, const int* in_sizes, int n_in,
                              void* d_out, int out_size, void* d_ws, size_t ws_size,
                              hipStream_t stream) {
    const float* x    = (const float*)d_in[0];  // [64][512][512]
    const float* W    = (const float*)d_in[1];  // [512][1024]
    const float* bias = (const float*)d_in[2];  // [1024]
    float* out = (float*)d_out;

    _Float16* xhi = (_Float16*)d_ws;
    _Float16* xlo = xhi + (size_t)NB * NK * NT;
    _Float16* whi = xlo + (size_t)NB * NK * NT;
    _Float16* wlo = whi + (size_t)NK * NH;

    split_tc<<<dim3(16, 4, 33), 256, 0, stream>>>(x, W, xhi, xlo, whi, wlo);
    fused_main<<<dim3(NB, NH / HB), 512, 0, stream>>>(xhi, xlo, whi, wlo, bias, out);
}